// Round 9
// baseline (216.608 us; speedup 1.0000x reference)
//
#include <hip/hip_runtime.h>

constexpr int N_ROWS = 131072;
constexpr int DIM    = 512;
constexpr int KP     = 512;
constexpr int BM     = 64;        // rows per block (4 waves x 16 rows)
constexpr int PC     = 64;        // panel cols
constexpr int NP     = KP / PC;   // 8 panels
// half-stage = 64 cols x 256 K fp8 = 1024 x 16B units = 16 KB, double-buffered

constexpr float PSCALE = 131072.0f;            // 2^17: P -> fp8 normal range
constexpr float DFACT  = 1.52587890625e-5f;    // 2 / 2^17

typedef float f32x4 __attribute__((ext_vector_type(4)));

__device__ inline unsigned cvtpk_fp8(float a, float b) {
    unsigned r = 0;   // "+v": high 16 bits preserved (= 0)
    asm volatile("v_cvt_pk_fp8_f32 %0, %1, %2" : "+v"(r) : "v"(a), "v"(b));
    return r;
}
__device__ inline void gload_lds16(const unsigned char* g, unsigned char* l) {
    // LDS dest must be WAVE-UNIFORM; HW adds lane*16.
    __builtin_amdgcn_global_load_lds(
        (const __attribute__((address_space(1))) unsigned*)g,
        (__attribute__((address_space(3))) unsigned*)l, 16, 0, 0);
}

// ---------------------------------------------------------------------------
// prep: pn[c] = ||P[c]||^2 (fp32, unscaled); Pq = fp8(P * 2^17) blocked by
// half-stage: 8B unit (c, ku8=k/8) -> byte
//   ((p*2 + ku8/32)*1024 + (ku8%32)*32 + (c%64)/2)*16 + (c%2)*8,  p=c/64.
// Exactly the linear order vq stages into LDS.
// ---------------------------------------------------------------------------
__global__ void prep_kernel(const float* __restrict__ P, float* __restrict__ pn,
                            unsigned char* __restrict__ Pq) {
    const int c = blockIdx.x, l = threadIdx.x;   // l = k-unit 0..63
    const float* row = P + (size_t)c * DIM;
    float4 a = *reinterpret_cast<const float4*>(row + l * 8);
    float4 b = *reinterpret_cast<const float4*>(row + l * 8 + 4);
    float s = a.x*a.x + a.y*a.y + a.z*a.z + a.w*a.w
            + b.x*b.x + b.y*b.y + b.z*b.z + b.w*b.w;
    unsigned lo = cvtpk_fp8(a.x * PSCALE, a.y * PSCALE)
                | (cvtpk_fp8(a.z * PSCALE, a.w * PSCALE) << 16);
    unsigned hi = cvtpk_fp8(b.x * PSCALE, b.y * PSCALE)
                | (cvtpk_fp8(b.z * PSCALE, b.w * PSCALE) << 16);
    unsigned long long v = (unsigned long long)lo | ((unsigned long long)hi << 32);
    const int p = c >> 6, col = c & 63, h = l >> 5, kul = l & 31;
    const size_t off =
        (size_t)((p * 2 + h) * 1024 + kul * 32 + (col >> 1)) * 16 + (col & 1) * 8;
    *reinterpret_cast<unsigned long long*>(Pq + off) = v;
#pragma unroll
    for (int o = 32; o > 0; o >>= 1) s += __shfl_down(s, o);
    if (l == 0) pn[c] = s;
}

// ---------------------------------------------------------------------------
// vq: wave w owns rows w*16..+15; A = fp8(X), full K=512, in 32 VGPRs.
// 8 panels x 64 cols; per panel 2 half-K stages (16 KB) double-buffered with
// counted vmcnt(4). Per half-phase per wave: 32 MFMA fp8, 32 ds_read_b64.
// Argmin wave-private; loss analytic: sum(best) + sum(||x||^2).
// ---------------------------------------------------------------------------
__global__ __launch_bounds__(256, 4)
void vq_kernel(const float* __restrict__ X, const float* __restrict__ P,
               const unsigned char* __restrict__ Pq, const float* __restrict__ pn,
               float* __restrict__ out, double* __restrict__ lsum) {
    __shared__ __align__(16) unsigned char Bs[2][16384];  // 2 x 16 KB
    __shared__ float pn_s[KP];
    __shared__ int   idx_s[BM];
    __shared__ float wls[4];

    const int tid  = threadIdx.x;
    const int lane = tid & 63;
    const int wid  = tid >> 6;
    const int lr   = lane & 15;   // A row-in-wave / B col-in-tile
    const int lg   = lane >> 4;   // k-subgroup
    const size_t row0 = (size_t)blockIdx.x * BM;

    auto STAGE = [&](int hs, int buf) {
        const unsigned char* src = Pq + ((size_t)hs * 1024 + wid * 64 + lane) * 16;
        unsigned char* dst = &Bs[buf][(wid * 64) * 16];   // wave-uniform base
#pragma unroll
        for (int i = 0; i < 4; ++i)
            gload_lds16(src + (size_t)i * 256 * 16, dst + (size_t)i * 256 * 16);
    };

    STAGE(0, 0);   // prefetch panel0/half0; latency hides under A-load

    pn_s[tid]       = pn[tid];
    pn_s[tid + 256] = pn[tid + 256];

    // ---- A: X -> fp8 registers (16 x i64) + ||x||^2 (fp32) ----
    long long a[16];
    float xsq = 0.f;
    const float* xb = X + (row0 + wid * 16 + lr) * DIM + lg * 8;
#pragma unroll
    for (int kk = 0; kk < 16; ++kk) {
        float4 v0 = *reinterpret_cast<const float4*>(xb + kk * 32);
        float4 v1 = *reinterpret_cast<const float4*>(xb + kk * 32 + 4);
        xsq += v0.x*v0.x + v0.y*v0.y + v0.z*v0.z + v0.w*v0.w
             + v1.x*v1.x + v1.y*v1.y + v1.z*v1.z + v1.w*v1.w;
        unsigned lo = cvtpk_fp8(v0.x, v0.y) | (cvtpk_fp8(v0.z, v0.w) << 16);
        unsigned hi = cvtpk_fp8(v1.x, v1.y) | (cvtpk_fp8(v1.z, v1.w) << 16);
        a[kk] = (long long)((unsigned long long)lo |
                            ((unsigned long long)hi << 32));
    }

    float bestv[4];
    int   besti[4];
#pragma unroll
    for (int j = 0; j < 4; ++j) { bestv[j] = 3.4e38f; besti[j] = 0; }

    f32x4 acc[4];
#pragma unroll
    for (int ct = 0; ct < 4; ++ct) acc[ct] = {0.f, 0.f, 0.f, 0.f};

#define COMPUTE_HALF(H, BUF)                                                   \
    {                                                                          \
        __builtin_amdgcn_s_setprio(1);                                         \
        _Pragma("unroll")                                                      \
        for (int kk = 0; kk < 8; ++kk) {                                       \
            const unsigned char* bb = &Bs[BUF][(kk * 4 + lg) * 512 + lr * 8];  \
            _Pragma("unroll")                                                  \
            for (int ct = 0; ct < 4; ++ct) {                                   \
                long long b = *reinterpret_cast<const long long*>(bb + ct * 128); \
                acc[ct] = __builtin_amdgcn_mfma_f32_16x16x32_fp8_fp8(          \
                    a[(H) * 8 + kk], b, acc[ct], 0, 0, 0);                     \
            }                                                                  \
        }                                                                      \
        __builtin_amdgcn_s_setprio(0);                                         \
    }

    for (int p = 0; p < NP; ++p) {
        // ---- half 0: compute buf0 (stage 2p); prefetch 2p+1 -> buf1 ----
        __builtin_amdgcn_s_barrier();            // all waves consumed buf1
        STAGE(2 * p + 1, 1);
        asm volatile("s_waitcnt vmcnt(4)" ::: "memory");  // stage 2p landed
        __builtin_amdgcn_s_barrier();
        __builtin_amdgcn_sched_barrier(0);
        COMPUTE_HALF(0, 0)

        // ---- half 1: compute buf1 (stage 2p+1); prefetch 2p+2 -> buf0 ----
        __builtin_amdgcn_s_barrier();            // all waves consumed buf0
        if (p + 1 < NP) {
            STAGE(2 * p + 2, 0);
            asm volatile("s_waitcnt vmcnt(4)" ::: "memory");
        } else {
            asm volatile("s_waitcnt vmcnt(0)" ::: "memory");
        }
        __builtin_amdgcn_s_barrier();
        __builtin_amdgcn_sched_barrier(0);
        COMPUTE_HALF(1, 1)

        // ---- fold panel (64 cols) into running best; ascending index ----
#pragma unroll
        for (int ct = 0; ct < 4; ++ct) {
            const float pnv = pn_s[p * PC + ct * 16 + lr];
            const int   ci  = p * PC + ct * 16 + lr;
#pragma unroll
            for (int j = 0; j < 4; ++j) {
                float d = fmaf(-DFACT, acc[ct][j], pnv);
                if (d < bestv[j]) { bestv[j] = d; besti[j] = ci; }
            }
            acc[ct] = {0.f, 0.f, 0.f, 0.f};
        }
    }
#undef COMPUTE_HALF

    // ---- wave-private argmin across the 16 col-holding lanes ----
#pragma unroll
    for (int j = 0; j < 4; ++j) {
#pragma unroll
        for (int m = 1; m < 16; m <<= 1) {
            float ov = __shfl_xor(bestv[j], m);
            int   oi = __shfl_xor(besti[j], m);
            if (ov < bestv[j] || (ov == bestv[j] && oi < besti[j])) {
                bestv[j] = ov; besti[j] = oi;
            }
        }
        if (lr == 0) idx_s[wid * 16 + lg * 4 + j] = besti[j];
    }
    // loss partial: best dists (lr==0 lanes) + ||x||^2 (all lanes)
    float lcl = xsq + (lr == 0 ? bestv[0] + bestv[1] + bestv[2] + bestv[3] : 0.f);
#pragma unroll
    for (int o = 32; o > 0; o >>= 1) lcl += __shfl_down(lcl, o);
    if (lane == 0) wls[wid] = lcl;
    __syncthreads();
    if (tid == 0)
        atomicAdd(lsum, (double)wls[0] + (double)wls[1]
                      + (double)wls[2] + (double)wls[3]);

    // ---- epilogue: out[r] = P[idx[r]] (P is L2-hot) ----
#pragma unroll 4
    for (int i = 0; i < 32; ++i) {
        int q = tid + i * 256;
        int r = q >> 7, f4 = q & 127;
        float4 pv = *reinterpret_cast<const float4*>(
            P + (size_t)idx_s[r] * DIM + f4 * 4);
        *reinterpret_cast<float4*>(out + (row0 + r) * DIM + f4 * 4) = pv;
    }
}

__global__ void finalize_kernel(const double* __restrict__ lsum,
                                float* __restrict__ out_loss) {
    out_loss[0] = (float)(1.25 * lsum[0] / ((double)N_ROWS * (double)DIM));
}

extern "C" void kernel_launch(void* const* d_in, const int* in_sizes, int n_in,
                              void* d_out, int out_size, void* d_ws, size_t ws_size,
                              hipStream_t stream) {
    const float* X = (const float*)d_in[0];
    const float* P = (const float*)d_in[1];
    float* out = (float*)d_out;

    // ws: [0,8) lsum; [256,+2K) pn; [4096,+256K) Pq fp8
    double*        lsum = (double*)d_ws;
    float*         pn   = (float*)((char*)d_ws + 256);
    unsigned char* Pq   = (unsigned char*)d_ws + 4096;

    (void)hipMemsetAsync(d_ws, 0, 64, stream);
    prep_kernel<<<KP, 64, 0, stream>>>(P, pn, Pq);
    vq_kernel<<<N_ROWS / BM, 256, 0, stream>>>(X, P, Pq, pn, out, lsum);
    finalize_kernel<<<1, 1, 0, stream>>>(lsum, out + (size_t)N_ROWS * DIM);
    (void)hipMemcpyAsync(out + (size_t)N_ROWS * DIM + 1, P,
                         (size_t)KP * DIM * sizeof(float),
                         hipMemcpyDeviceToDevice, stream);
}

// Round 10
// 214.285 us; speedup vs baseline: 1.0108x; 1.0108x over previous
//
#include <hip/hip_runtime.h>

constexpr int N_ROWS = 131072;
constexpr int DIM    = 512;
constexpr int KP     = 512;
constexpr int BM     = 64;        // rows per block (4 waves x 16 rows)
constexpr int PC     = 64;        // panel cols
constexpr int NP     = KP / PC;   // 8 panels
// half-stage = 64 cols x 256 K fp8 = 1024 x 16B units = 16 KB, double-buffered

constexpr float PSCALE = 131072.0f;            // 2^17: P -> fp8 normal range
constexpr float DFACT  = 1.52587890625e-5f;    // 2 / 2^17

typedef float f32x4 __attribute__((ext_vector_type(4)));

__device__ inline unsigned cvtpk_fp8(float a, float b) {
    unsigned r = 0;   // "+v": high 16 bits preserved (= 0)
    asm volatile("v_cvt_pk_fp8_f32 %0, %1, %2" : "+v"(r) : "v"(a), "v"(b));
    return r;
}
__device__ inline void gload_lds16(const unsigned char* g, unsigned char* l) {
    // LDS dest must be WAVE-UNIFORM; HW adds lane*16.
    __builtin_amdgcn_global_load_lds(
        (const __attribute__((address_space(1))) unsigned*)g,
        (__attribute__((address_space(3))) unsigned*)l, 16, 0, 0);
}

// ---------------------------------------------------------------------------
// prep: pn[c] = ||P[c]||^2 (fp32, unscaled); Pq = fp8(P * 2^17) blocked by
// half-stage: 8B unit (c, ku8=k/8) -> byte
//   ((p*2 + ku8/32)*1024 + (ku8%32)*32 + (c%64)/2)*16 + (c%2)*8,  p=c/64.
// Exactly the linear order vq stages into LDS.
// ---------------------------------------------------------------------------
__global__ void prep_kernel(const float* __restrict__ P, float* __restrict__ pn,
                            unsigned char* __restrict__ Pq) {
    const int c = blockIdx.x, l = threadIdx.x;   // l = k-unit 0..63
    const float* row = P + (size_t)c * DIM;
    float4 a = *reinterpret_cast<const float4*>(row + l * 8);
    float4 b = *reinterpret_cast<const float4*>(row + l * 8 + 4);
    float s = a.x*a.x + a.y*a.y + a.z*a.z + a.w*a.w
            + b.x*b.x + b.y*b.y + b.z*b.z + b.w*b.w;
    unsigned lo = cvtpk_fp8(a.x * PSCALE, a.y * PSCALE)
                | (cvtpk_fp8(a.z * PSCALE, a.w * PSCALE) << 16);
    unsigned hi = cvtpk_fp8(b.x * PSCALE, b.y * PSCALE)
                | (cvtpk_fp8(b.z * PSCALE, b.w * PSCALE) << 16);
    unsigned long long v = (unsigned long long)lo | ((unsigned long long)hi << 32);
    const int p = c >> 6, col = c & 63, h = l >> 5, kul = l & 31;
    const size_t off =
        (size_t)((p * 2 + h) * 1024 + kul * 32 + (col >> 1)) * 16 + (col & 1) * 8;
    *reinterpret_cast<unsigned long long*>(Pq + off) = v;
#pragma unroll
    for (int o = 32; o > 0; o >>= 1) s += __shfl_down(s, o);
    if (l == 0) pn[c] = s;
}

// ---------------------------------------------------------------------------
// vq: wave w owns rows w*16..+15; A = fp8(X), full K=512, in 16 NAMED i64
// registers (no array -> no scratch). 8 panels x 64 cols; per panel 2 half-K
// stages (16 KB) double-buffered with counted vmcnt(4).
// Argmin wave-private; loss analytic: sum(best) + sum(||x||^2).
// ---------------------------------------------------------------------------
__global__ __launch_bounds__(256, 4)
void vq_kernel(const float* __restrict__ X, const float* __restrict__ P,
               const unsigned char* __restrict__ Pq, const float* __restrict__ pn,
               float* __restrict__ out, double* __restrict__ lsum) {
    __shared__ __align__(16) unsigned char Bs[2][16384];  // 2 x 16 KB
    __shared__ float pn_s[KP];
    __shared__ int   idx_s[BM];
    __shared__ float wls[4];

    const int tid  = threadIdx.x;
    const int lane = tid & 63;
    const int wid  = tid >> 6;
    const int lr   = lane & 15;   // A row-in-wave / B col-in-tile
    const int lg   = lane >> 4;   // k-subgroup
    const size_t row0 = (size_t)blockIdx.x * BM;

    auto STAGE = [&](int hs, int buf) {
        const unsigned char* src = Pq + ((size_t)hs * 1024 + wid * 64 + lane) * 16;
        unsigned char* dst = &Bs[buf][(wid * 64) * 16];   // wave-uniform base
#pragma unroll
        for (int i = 0; i < 4; ++i)
            gload_lds16(src + (size_t)i * 256 * 16, dst + (size_t)i * 256 * 16);
    };

    STAGE(0, 0);   // prefetch panel0/half0; latency hides under A-load

    pn_s[tid]       = pn[tid];
    pn_s[tid + 256] = pn[tid + 256];

    // ---- A: X -> fp8 in 16 NAMED i64 regs + ||x||^2 (fp32) ----
    float xsq = 0.f;
    const float* xb = X + (row0 + wid * 16 + lr) * DIM + lg * 8;

#define ALOAD(KK, areg)                                                        \
    long long areg;                                                            \
    {                                                                          \
        float4 v0 = *reinterpret_cast<const float4*>(xb + (KK) * 32);          \
        float4 v1 = *reinterpret_cast<const float4*>(xb + (KK) * 32 + 4);      \
        xsq += v0.x*v0.x + v0.y*v0.y + v0.z*v0.z + v0.w*v0.w                   \
             + v1.x*v1.x + v1.y*v1.y + v1.z*v1.z + v1.w*v1.w;                  \
        unsigned lo = cvtpk_fp8(v0.x, v0.y) | (cvtpk_fp8(v0.z, v0.w) << 16);   \
        unsigned hi = cvtpk_fp8(v1.x, v1.y) | (cvtpk_fp8(v1.z, v1.w) << 16);   \
        areg = (long long)((unsigned long long)lo |                            \
                           ((unsigned long long)hi << 32));                    \
    }
    ALOAD(0,  a0)  ALOAD(1,  a1)  ALOAD(2,  a2)  ALOAD(3,  a3)
    ALOAD(4,  a4)  ALOAD(5,  a5)  ALOAD(6,  a6)  ALOAD(7,  a7)
    ALOAD(8,  a8)  ALOAD(9,  a9)  ALOAD(10, a10) ALOAD(11, a11)
    ALOAD(12, a12) ALOAD(13, a13) ALOAD(14, a14) ALOAD(15, a15)
#undef ALOAD

    float bv0 = 3.4e38f, bv1 = 3.4e38f, bv2 = 3.4e38f, bv3 = 3.4e38f;
    int   bi0 = 0, bi1 = 0, bi2 = 0, bi3 = 0;
    f32x4 acc0 = {0.f, 0.f, 0.f, 0.f}, acc1 = {0.f, 0.f, 0.f, 0.f};
    f32x4 acc2 = {0.f, 0.f, 0.f, 0.f}, acc3 = {0.f, 0.f, 0.f, 0.f};

#define MFMA_K(BUF, KK, areg)                                                  \
    {                                                                          \
        const unsigned char* bb = &Bs[BUF][((KK) * 4 + lg) * 512 + lr * 8];    \
        long long b0 = *reinterpret_cast<const long long*>(bb);                \
        long long b1 = *reinterpret_cast<const long long*>(bb + 128);          \
        long long b2 = *reinterpret_cast<const long long*>(bb + 256);          \
        long long b3 = *reinterpret_cast<const long long*>(bb + 384);          \
        acc0 = __builtin_amdgcn_mfma_f32_16x16x32_fp8_fp8(areg, b0, acc0, 0, 0, 0); \
        acc1 = __builtin_amdgcn_mfma_f32_16x16x32_fp8_fp8(areg, b1, acc1, 0, 0, 0); \
        acc2 = __builtin_amdgcn_mfma_f32_16x16x32_fp8_fp8(areg, b2, acc2, 0, 0, 0); \
        acc3 = __builtin_amdgcn_mfma_f32_16x16x32_fp8_fp8(areg, b3, acc3, 0, 0, 0); \
    }
#define COMPUTE_HALF(BUF, A0, A1, A2, A3, A4, A5, A6, A7)                      \
    __builtin_amdgcn_s_setprio(1);                                             \
    MFMA_K(BUF, 0, A0) MFMA_K(BUF, 1, A1) MFMA_K(BUF, 2, A2)                   \
    MFMA_K(BUF, 3, A3) MFMA_K(BUF, 4, A4) MFMA_K(BUF, 5, A5)                   \
    MFMA_K(BUF, 6, A6) MFMA_K(BUF, 7, A7)                                      \
    __builtin_amdgcn_s_setprio(0);

#define FOLD_CT(accv, CT)                                                      \
    {                                                                          \
        const float pnv = pn_s[p * PC + (CT) * 16 + lr];                       \
        const int   ci  = p * PC + (CT) * 16 + lr;                             \
        float d;                                                               \
        d = fmaf(-DFACT, accv[0], pnv);                                        \
        if (d < bv0) { bv0 = d; bi0 = ci; }                                    \
        d = fmaf(-DFACT, accv[1], pnv);                                        \
        if (d < bv1) { bv1 = d; bi1 = ci; }                                    \
        d = fmaf(-DFACT, accv[2], pnv);                                        \
        if (d < bv2) { bv2 = d; bi2 = ci; }                                    \
        d = fmaf(-DFACT, accv[3], pnv);                                        \
        if (d < bv3) { bv3 = d; bi3 = ci; }                                    \
        accv = (f32x4){0.f, 0.f, 0.f, 0.f};                                    \
    }

    for (int p = 0; p < NP; ++p) {
        // ---- half 0: compute buf0 (stage 2p); prefetch 2p+1 -> buf1 ----
        __builtin_amdgcn_s_barrier();            // all waves consumed buf1
        STAGE(2 * p + 1, 1);
        asm volatile("s_waitcnt vmcnt(4)" ::: "memory");  // stage 2p landed
        __builtin_amdgcn_s_barrier();
        __builtin_amdgcn_sched_barrier(0);
        COMPUTE_HALF(0, a0, a1, a2, a3, a4, a5, a6, a7)

        // ---- half 1: compute buf1 (stage 2p+1); prefetch 2p+2 -> buf0 ----
        __builtin_amdgcn_s_barrier();            // all waves consumed buf0
        if (p + 1 < NP) {
            STAGE(2 * p + 2, 0);
            asm volatile("s_waitcnt vmcnt(4)" ::: "memory");
        } else {
            asm volatile("s_waitcnt vmcnt(0)" ::: "memory");
        }
        __builtin_amdgcn_s_barrier();
        __builtin_amdgcn_sched_barrier(0);
        COMPUTE_HALF(1, a8, a9, a10, a11, a12, a13, a14, a15)

        // ---- fold panel (64 cols) into running best; ascending index ----
        FOLD_CT(acc0, 0) FOLD_CT(acc1, 1) FOLD_CT(acc2, 2) FOLD_CT(acc3, 3)
    }
#undef COMPUTE_HALF
#undef MFMA_K
#undef FOLD_CT

    // ---- wave-private argmin across the 16 col-holding lanes ----
#define MERGE(bv, bi, SLOT)                                                    \
    {                                                                          \
        _Pragma("unroll")                                                      \
        for (int m = 1; m < 16; m <<= 1) {                                     \
            float ov = __shfl_xor(bv, m);                                      \
            int   oi = __shfl_xor(bi, m);                                      \
            if (ov < bv || (ov == bv && oi < bi)) { bv = ov; bi = oi; }        \
        }                                                                      \
        if (lr == 0) idx_s[wid * 16 + lg * 4 + (SLOT)] = bi;                   \
    }
    MERGE(bv0, bi0, 0) MERGE(bv1, bi1, 1) MERGE(bv2, bi2, 2) MERGE(bv3, bi3, 3)
#undef MERGE

    // loss partial: best dists (lr==0 lanes) + ||x||^2 (all lanes)
    float lcl = xsq + (lr == 0 ? bv0 + bv1 + bv2 + bv3 : 0.f);
#pragma unroll
    for (int o = 32; o > 0; o >>= 1) lcl += __shfl_down(lcl, o);
    if (lane == 0) wls[wid] = lcl;
    __syncthreads();
    if (tid == 0)
        atomicAdd(lsum, (double)wls[0] + (double)wls[1]
                      + (double)wls[2] + (double)wls[3]);

    // ---- epilogue: out[r] = P[idx[r]] (P is L2-hot) ----
#pragma unroll 4
    for (int i = 0; i < 32; ++i) {
        int q = tid + i * 256;
        int r = q >> 7, f4 = q & 127;
        float4 pv = *reinterpret_cast<const float4*>(
            P + (size_t)idx_s[r] * DIM + f4 * 4);
        *reinterpret_cast<float4*>(out + (row0 + r) * DIM + f4 * 4) = pv;
    }
}

__global__ void finalize_kernel(const double* __restrict__ lsum,
                                float* __restrict__ out_loss) {
    out_loss[0] = (float)(1.25 * lsum[0] / ((double)N_ROWS * (double)DIM));
}

extern "C" void kernel_launch(void* const* d_in, const int* in_sizes, int n_in,
                              void* d_out, int out_size, void* d_ws, size_t ws_size,
                              hipStream_t stream) {
    const float* X = (const float*)d_in[0];
    const float* P = (const float*)d_in[1];
    float* out = (float*)d_out;

    // ws: [0,8) lsum; [256,+2K) pn; [4096,+256K) Pq fp8
    double*        lsum = (double*)d_ws;
    float*         pn   = (float*)((char*)d_ws + 256);
    unsigned char* Pq   = (unsigned char*)d_ws + 4096;

    (void)hipMemsetAsync(d_ws, 0, 64, stream);
    prep_kernel<<<KP, 64, 0, stream>>>(P, pn, Pq);
    vq_kernel<<<N_ROWS / BM, 256, 0, stream>>>(X, P, Pq, pn, out, lsum);
    finalize_kernel<<<1, 1, 0, stream>>>(lsum, out + (size_t)N_ROWS * DIM);
    (void)hipMemcpyAsync(out + (size_t)N_ROWS * DIM + 1, P,
                         (size_t)KP * DIM * sizeof(float),
                         hipMemcpyDeviceToDevice, stream);
}

// Round 11
// 194.536 us; speedup vs baseline: 1.1135x; 1.1015x over previous
//
#include <hip/hip_runtime.h>

constexpr int N_ROWS = 131072;
constexpr int DIM    = 512;
constexpr int KP     = 512;
constexpr int BM     = 64;        // rows per block (4 waves x 16 rows)
constexpr int SC     = 64;        // cols per stage (full K=512 each)
constexpr int NS     = KP / SC;   // 8 stages
// stage = 64 cols x 512 K fp8 = 32 KB; double-buffered = 64 KB LDS

constexpr float PSCALE = 131072.0f;            // 2^17: P -> fp8 normal range
constexpr float DFACT  = 1.52587890625e-5f;    // 2 / 2^17

typedef float f32x4 __attribute__((ext_vector_type(4)));

__device__ inline unsigned cvtpk_fp8(float a, float b) {
    unsigned r = 0;   // "+v": high 16 bits preserved (= 0)
    asm volatile("v_cvt_pk_fp8_f32 %0, %1, %2" : "+v"(r) : "v"(a), "v"(b));
    return r;
}
__device__ inline void gload_lds16(const unsigned char* g, unsigned char* l) {
    // LDS dest must be WAVE-UNIFORM; HW adds lane*16.
    __builtin_amdgcn_global_load_lds(
        (const __attribute__((address_space(1))) unsigned*)g,
        (__attribute__((address_space(3))) unsigned*)l, 16, 0, 0);
}

// ---------------------------------------------------------------------------
// prep: pn[c] = ||P[c]||^2 (fp32, unscaled); Pq = fp8(P * 2^17) blocked by
// stage s=c/64 (64 cols x full K). 8B k-octet (c, ku=k/8) -> byte
//   s*32768 + (ku*32 + (c%64)/2)*16 + (c%2)*8.
// Exactly the linear order vq stages into LDS.
// ---------------------------------------------------------------------------
__global__ void prep_kernel(const float* __restrict__ P, float* __restrict__ pn,
                            unsigned char* __restrict__ Pq) {
    const int c = blockIdx.x, l = threadIdx.x;   // l = k-octet 0..63
    const float* row = P + (size_t)c * DIM;
    float4 a = *reinterpret_cast<const float4*>(row + l * 8);
    float4 b = *reinterpret_cast<const float4*>(row + l * 8 + 4);
    float s = a.x*a.x + a.y*a.y + a.z*a.z + a.w*a.w
            + b.x*b.x + b.y*b.y + b.z*b.z + b.w*b.w;
    unsigned lo = cvtpk_fp8(a.x * PSCALE, a.y * PSCALE)
                | (cvtpk_fp8(a.z * PSCALE, a.w * PSCALE) << 16);
    unsigned hi = cvtpk_fp8(b.x * PSCALE, b.y * PSCALE)
                | (cvtpk_fp8(b.z * PSCALE, b.w * PSCALE) << 16);
    unsigned long long v = (unsigned long long)lo | ((unsigned long long)hi << 32);
    const int st = c >> 6, cl = c & 63;
    const size_t off =
        (size_t)st * 32768 + (size_t)(l * 32 + (cl >> 1)) * 16 + (cl & 1) * 8;
    *reinterpret_cast<unsigned long long*>(Pq + off) = v;
#pragma unroll
    for (int o = 32; o > 0; o >>= 1) s += __shfl_down(s, o);
    if (l == 0) pn[c] = s;
}

// ---------------------------------------------------------------------------
// vq: wave w owns rows w*16..+15; A = fp8(X), full K=512, 16 named i64 regs.
// 8 stages of {64 cols x full K} (32 KB), double-buffered, counted vmcnt(8).
// Per stage per wave: 64 MFMA fp8 + fold. launch_bounds(256,2): 256-VGPR cap
// so the A regs CANNOT spill; occupancy is LDS-bound at 2 blocks/CU.
// ---------------------------------------------------------------------------
__global__ __launch_bounds__(256, 2)
void vq_kernel(const float* __restrict__ X, const float* __restrict__ P,
               const unsigned char* __restrict__ Pq, const float* __restrict__ pn,
               float* __restrict__ out, double* __restrict__ lsum) {
    __shared__ __align__(16) unsigned char Bs[2][32768];  // 2 x 32 KB
    __shared__ float pn_s[KP];
    __shared__ int   idx_s[BM];
    __shared__ float wls[4];

    const int tid  = threadIdx.x;
    const int lane = tid & 63;
    const int wid  = tid >> 6;
    const int lr   = lane & 15;   // A row-in-wave / B col-in-tile
    const int lg   = lane >> 4;   // k-subgroup
    const size_t row0 = (size_t)blockIdx.x * BM;

    auto STAGE = [&](int s, int buf) {
        const unsigned char* src = Pq + (size_t)s * 32768 + (wid * 64 + lane) * 16;
        unsigned char* dst = &Bs[buf][(wid * 64) * 16];   // wave-uniform base
#pragma unroll
        for (int i = 0; i < 8; ++i)
            gload_lds16(src + (size_t)i * 4096, dst + (size_t)i * 4096);
    };

    STAGE(0, 0);   // prefetch stage 0; latency hides under A-load

    pn_s[tid]       = pn[tid];
    pn_s[tid + 256] = pn[tid + 256];

    // ---- A: X -> fp8 in 16 NAMED i64 regs + ||x||^2 (fp32) ----
    float xsq = 0.f;
    const float* xb = X + (row0 + wid * 16 + lr) * DIM + lg * 8;

#define ALOAD(KK, areg)                                                        \
    long long areg;                                                            \
    {                                                                          \
        float4 v0 = *reinterpret_cast<const float4*>(xb + (KK) * 32);          \
        float4 v1 = *reinterpret_cast<const float4*>(xb + (KK) * 32 + 4);      \
        xsq += v0.x*v0.x + v0.y*v0.y + v0.z*v0.z + v0.w*v0.w                   \
             + v1.x*v1.x + v1.y*v1.y + v1.z*v1.z + v1.w*v1.w;                  \
        unsigned lo = cvtpk_fp8(v0.x, v0.y) | (cvtpk_fp8(v0.z, v0.w) << 16);   \
        unsigned hi = cvtpk_fp8(v1.x, v1.y) | (cvtpk_fp8(v1.z, v1.w) << 16);   \
        areg = (long long)((unsigned long long)lo |                            \
                           ((unsigned long long)hi << 32));                    \
    }
    ALOAD(0,  a0)  ALOAD(1,  a1)  ALOAD(2,  a2)  ALOAD(3,  a3)
    ALOAD(4,  a4)  ALOAD(5,  a5)  ALOAD(6,  a6)  ALOAD(7,  a7)
    ALOAD(8,  a8)  ALOAD(9,  a9)  ALOAD(10, a10) ALOAD(11, a11)
    ALOAD(12, a12) ALOAD(13, a13) ALOAD(14, a14) ALOAD(15, a15)
#undef ALOAD

    float bv0 = 3.4e38f, bv1 = 3.4e38f, bv2 = 3.4e38f, bv3 = 3.4e38f;
    int   bi0 = 0, bi1 = 0, bi2 = 0, bi3 = 0;
    f32x4 acc0 = {0.f, 0.f, 0.f, 0.f}, acc1 = {0.f, 0.f, 0.f, 0.f};
    f32x4 acc2 = {0.f, 0.f, 0.f, 0.f}, acc3 = {0.f, 0.f, 0.f, 0.f};

#define MFMA_K(KK, areg)                                                       \
    {                                                                          \
        const unsigned char* bb = bsp + ((KK) * 4 + lg) * 512 + lr * 8;        \
        long long b0 = *reinterpret_cast<const long long*>(bb);                \
        long long b1 = *reinterpret_cast<const long long*>(bb + 128);          \
        long long b2 = *reinterpret_cast<const long long*>(bb + 256);          \
        long long b3 = *reinterpret_cast<const long long*>(bb + 384);          \
        acc0 = __builtin_amdgcn_mfma_f32_16x16x32_fp8_fp8(areg, b0, acc0, 0, 0, 0); \
        acc1 = __builtin_amdgcn_mfma_f32_16x16x32_fp8_fp8(areg, b1, acc1, 0, 0, 0); \
        acc2 = __builtin_amdgcn_mfma_f32_16x16x32_fp8_fp8(areg, b2, acc2, 0, 0, 0); \
        acc3 = __builtin_amdgcn_mfma_f32_16x16x32_fp8_fp8(areg, b3, acc3, 0, 0, 0); \
    }

#define FOLD_CT(accv, CT)                                                      \
    {                                                                          \
        const float pnv = pn_s[s * SC + (CT) * 16 + lr];                       \
        const int   ci  = s * SC + (CT) * 16 + lr;                             \
        float d;                                                               \
        d = fmaf(-DFACT, accv[0], pnv);                                        \
        if (d < bv0) { bv0 = d; bi0 = ci; }                                    \
        d = fmaf(-DFACT, accv[1], pnv);                                        \
        if (d < bv1) { bv1 = d; bi1 = ci; }                                    \
        d = fmaf(-DFACT, accv[2], pnv);                                        \
        if (d < bv2) { bv2 = d; bi2 = ci; }                                    \
        d = fmaf(-DFACT, accv[3], pnv);                                        \
        if (d < bv3) { bv3 = d; bi3 = ci; }                                    \
        accv = (f32x4){0.f, 0.f, 0.f, 0.f};                                    \
    }

    for (int s = 0; s < NS; ++s) {
        __builtin_amdgcn_s_barrier();            // all waves done with buf s&1
        if (s + 1 < NS) {
            STAGE(s + 1, (s + 1) & 1);           // issue next stage's 8 loads
            asm volatile("s_waitcnt vmcnt(8)" ::: "memory");  // stage s landed
        } else {
            asm volatile("s_waitcnt vmcnt(0)" ::: "memory");
        }
        __builtin_amdgcn_s_barrier();
        __builtin_amdgcn_sched_barrier(0);

        const unsigned char* bsp = Bs[s & 1];
        __builtin_amdgcn_s_setprio(1);
        MFMA_K(0,  a0)  MFMA_K(1,  a1)  MFMA_K(2,  a2)  MFMA_K(3,  a3)
        MFMA_K(4,  a4)  MFMA_K(5,  a5)  MFMA_K(6,  a6)  MFMA_K(7,  a7)
        MFMA_K(8,  a8)  MFMA_K(9,  a9)  MFMA_K(10, a10) MFMA_K(11, a11)
        MFMA_K(12, a12) MFMA_K(13, a13) MFMA_K(14, a14) MFMA_K(15, a15)
        __builtin_amdgcn_s_setprio(0);

        FOLD_CT(acc0, 0) FOLD_CT(acc1, 1) FOLD_CT(acc2, 2) FOLD_CT(acc3, 3)
    }
#undef MFMA_K
#undef FOLD_CT

    // ---- wave-private argmin across the 16 col-holding lanes ----
#define MERGE(bv, bi, SLOT)                                                    \
    {                                                                          \
        _Pragma("unroll")                                                      \
        for (int m = 1; m < 16; m <<= 1) {                                     \
            float ov = __shfl_xor(bv, m);                                      \
            int   oi = __shfl_xor(bi, m);                                      \
            if (ov < bv || (ov == bv && oi < bi)) { bv = ov; bi = oi; }        \
        }                                                                      \
        if (lr == 0) idx_s[wid * 16 + lg * 4 + (SLOT)] = bi;                   \
    }
    MERGE(bv0, bi0, 0) MERGE(bv1, bi1, 1) MERGE(bv2, bi2, 2) MERGE(bv3, bi3, 3)
#undef MERGE

    // loss partial: best dists (lr==0 lanes) + ||x||^2 (all lanes)
    float lcl = xsq + (lr == 0 ? bv0 + bv1 + bv2 + bv3 : 0.f);
#pragma unroll
    for (int o = 32; o > 0; o >>= 1) lcl += __shfl_down(lcl, o);
    if (lane == 0) wls[wid] = lcl;
    __syncthreads();
    if (tid == 0)
        atomicAdd(lsum, (double)wls[0] + (double)wls[1]
                      + (double)wls[2] + (double)wls[3]);

    // ---- epilogue: out[r] = P[idx[r]] (P is L2-hot) ----
#pragma unroll 4
    for (int i = 0; i < 32; ++i) {
        int q = tid + i * 256;
        int r = q >> 7, f4 = q & 127;
        float4 pv = *reinterpret_cast<const float4*>(
            P + (size_t)idx_s[r] * DIM + f4 * 4);
        *reinterpret_cast<float4*>(out + (row0 + r) * DIM + f4 * 4) = pv;
    }
}

__global__ void finalize_kernel(const double* __restrict__ lsum,
                                float* __restrict__ out_loss) {
    out_loss[0] = (float)(1.25 * lsum[0] / ((double)N_ROWS * (double)DIM));
}

extern "C" void kernel_launch(void* const* d_in, const int* in_sizes, int n_in,
                              void* d_out, int out_size, void* d_ws, size_t ws_size,
                              hipStream_t stream) {
    const float* X = (const float*)d_in[0];
    const float* P = (const float*)d_in[1];
    float* out = (float*)d_out;

    // ws: [0,8) lsum; [256,+2K) pn; [4096,+256K) Pq fp8
    double*        lsum = (double*)d_ws;
    float*         pn   = (float*)((char*)d_ws + 256);
    unsigned char* Pq   = (unsigned char*)d_ws + 4096;

    (void)hipMemsetAsync(d_ws, 0, 64, stream);
    prep_kernel<<<KP, 64, 0, stream>>>(P, pn, Pq);
    vq_kernel<<<N_ROWS / BM, 256, 0, stream>>>(X, P, Pq, pn, out, lsum);
    finalize_kernel<<<1, 1, 0, stream>>>(lsum, out + (size_t)N_ROWS * DIM);
    (void)hipMemcpyAsync(out + (size_t)N_ROWS * DIM + 1, P,
                         (size_t)KP * DIM * sizeof(float),
                         hipMemcpyDeviceToDevice, stream);
}